// Round 3
// baseline (1063.738 us; speedup 1.0000x reference)
//
#include <hip/hip_runtime.h>
#include <math.h>

#define F_IN 128
#define H 16
#define C 40
#define K_HOPS 10
#define ALPHA 0.1f
#define BN_EPS 1e-5f

#define RB 512          // nodes per bucket
#define RB_BITS 9
#define NBKT_MAX 256    // ceil(100000/512)=196 <= 256

// ---------------- zero: cnt[n]=0, gbcnt=0, stats=0 ----------------
__global__ void k_zero(int* __restrict__ cnt, int* __restrict__ gbcnt,
                       float* __restrict__ stats, int n) {
    int id = blockIdx.x * blockDim.x + threadIdx.x;
    int stride = gridDim.x * blockDim.x;
    for (int i = id; i < n; i += stride) cnt[i] = 0;
    if (id < NBKT_MAX) gbcnt[id] = 0;
    if (id < 32) stats[id] = 0.0f;
}

// ---------------- degree histogram + bucket counts ----------------
__global__ __launch_bounds__(256) void k_degbk(const int* __restrict__ dst,
                                               int* __restrict__ cnt,
                                               int* __restrict__ gbcnt, int e) {
    __shared__ int hist[NBKT_MAX];
    int t = threadIdx.x;
    if (t < NBKT_MAX) hist[t] = 0;
    __syncthreads();
    int base = blockIdx.x * 4096;
    int endi = base + 4096; if (endi > e) endi = e;
    for (int i = base + t; i < endi; i += 256) {
        int d = dst[i];
        atomicAdd(&cnt[d], 1);
        atomicAdd(&hist[d >> RB_BITS], 1);
    }
    __syncthreads();
    if (t < NBKT_MAX && hist[t]) atomicAdd(&gbcnt[t], hist[t]);
}

// ---------------- dinv = rsqrt(deg+1) ----------------
__global__ void k_dinv(const int* __restrict__ cnt, float* __restrict__ dinv, int n) {
    int i = blockIdx.x * blockDim.x + threadIdx.x;
    if (i < n) dinv[i] = rsqrtf((float)(cnt[i] + 1));
}

// ---------------- exclusive scan of bucket counts (single block) ----------------
__global__ __launch_bounds__(256) void k_bscan(const int* __restrict__ gbcnt,
                                               int* __restrict__ gboff,
                                               int* __restrict__ gcur, int nbkt) {
    __shared__ int sd[256];
    int t = threadIdx.x;
    int v = (t < nbkt) ? gbcnt[t] : 0;
    sd[t] = v;
    __syncthreads();
    for (int off = 1; off < 256; off <<= 1) {
        int tmp = (t >= off) ? sd[t - off] : 0;
        __syncthreads();
        sd[t] += tmp;
        __syncthreads();
    }
    if (t < nbkt) { int o = sd[t] - v; gboff[t] = o; gcur[t] = o; }
    if (t == nbkt - 1) gboff[nbkt] = sd[t];
}

// ---------------- bin edges into bucket runs (dense writes) ----------------
#define BIN_CHUNK 4096   // 16 edges per thread
__global__ __launch_bounds__(256) void k_bin(const int* __restrict__ src,
                                             const int* __restrict__ dst,
                                             const float* __restrict__ dinv,
                                             int* __restrict__ gcur,
                                             int2* __restrict__ temp, int e) {
    __shared__ int hist[NBKT_MAX];
    __shared__ int lcur[NBKT_MAX];
    int t = threadIdx.x;
    if (t < NBKT_MAX) hist[t] = 0;
    __syncthreads();
    int base = blockIdx.x * BIN_CHUNK;
    int ss[16], dd[16];
#pragma unroll
    for (int i = 0; i < 16; ++i) {
        int idx = base + i * 256 + t;
        if (idx < e) {
            ss[i] = src[idx]; dd[i] = dst[idx];
            atomicAdd(&hist[dd[i] >> RB_BITS], 1);
        } else ss[i] = -1;
    }
    __syncthreads();
    if (t < NBKT_MAX) {
        int h = hist[t];
        lcur[t] = h ? atomicAdd(&gcur[t], h) : 0;
    }
    __syncthreads();
#pragma unroll
    for (int i = 0; i < 16; ++i) {
        if (ss[i] >= 0) {
            int s = ss[i], d = dd[i];
            float nrm = dinv[s] * dinv[d];
            int b = d >> RB_BITS;
            int pos = atomicAdd(&lcur[b], 1);
            temp[pos] = make_int2(s | ((d & (RB - 1)) << 17), __float_as_int(nrm));
        }
    }
}

// ---------------- h1 = x @ W1   [N,128] x [128,16] ----------------
__global__ __launch_bounds__(256) void k_mm1(const float* __restrict__ x,
                                             const float* __restrict__ W1,
                                             float* __restrict__ h1, int n) {
    __shared__ float xs[16 * 132];
    __shared__ float ws[128 * 16];
    int t = threadIdx.x;
    int node0 = blockIdx.x * 16;
#pragma unroll
    for (int r = 0; r < 8; ++r) {
        int idx = t + r * 256;
        int nl = idx >> 7, k = idx & 127;
        int nn = node0 + nl; if (nn >= n) nn = n - 1;
        xs[nl * 132 + k] = x[(size_t)nn * F_IN + k];
        ws[idx] = W1[idx];
    }
    __syncthreads();
    int nl = t >> 4, j = t & 15;
    float acc = 0.0f;
#pragma unroll 8
    for (int k = 0; k < 128; ++k)
        acc = fmaf(xs[nl * 132 + k], ws[k * 16 + j], acc);
    int node = node0 + nl;
    if (node < n) h1[(size_t)node * H + j] = acc;
}

// ---------------- bucket aggregation scan (shared by both convs) ----------------
__device__ __forceinline__ void bagg_scan(const int2* __restrict__ temp,
                                          const float* __restrict__ h,
                                          int start, int endi, int half,
                                          float* __restrict__ acc) {
    int t = threadIdx.x;
    int g = t >> 3;        // 0..31 entry groups
    int jj = t & 7;
    int k = start + g;
    for (; k + 32 < endi; k += 64) {
        int2 e0 = temp[k];
        int2 e1 = temp[k + 32];
        int s0 = e0.x & 0x1FFFF, dl0 = e0.x >> 17;
        int s1 = e1.x & 0x1FFFF, dl1 = e1.x >> 17;
        float v0 = h[(size_t)s0 * H + half * 8 + jj];
        float v1 = h[(size_t)s1 * H + half * 8 + jj];
        atomicAdd(&acc[dl0 * 9 + jj], v0 * __int_as_float(e0.y));
        atomicAdd(&acc[dl1 * 9 + jj], v1 * __int_as_float(e1.y));
    }
    if (k < endi) {
        int2 e0 = temp[k];
        int s0 = e0.x & 0x1FFFF, dl0 = e0.x >> 17;
        float v0 = h[(size_t)s0 * H + half * 8 + jj];
        atomicAdd(&acc[dl0 * 9 + jj], v0 * __int_as_float(e0.y));
    }
}

// ---------------- conv1: bucket agg + self + bias + ReLU + BN stats ----------------
__global__ __launch_bounds__(256) void k_bagg1(const int* __restrict__ gboff,
                                               const int2* __restrict__ temp,
                                               const float* __restrict__ h1,
                                               const float* __restrict__ dinv,
                                               const float* __restrict__ b1,
                                               float* __restrict__ hout,
                                               float* __restrict__ stats, int n) {
    __shared__ float acc[RB * 9];
    __shared__ float red[512];
    int t = threadIdx.x;
    int bkt = blockIdx.x >> 1, half = blockIdx.x & 1;
    for (int i = t; i < RB * 9; i += 256) acc[i] = 0.0f;
    __syncthreads();
    bagg_scan(temp, h1, gboff[bkt], gboff[bkt + 1], half, acc);
    __syncthreads();
    int jj = t & 7, dgrp = t >> 3;
    int j = half * 8 + jj;
    float bj = b1[j];
    float sv = 0.0f, sq = 0.0f;
    int node0 = bkt * RB;
#pragma unroll
    for (int k2 = 0; k2 < 16; ++k2) {
        int dl = dgrp + k2 * 32;
        int node = node0 + dl;
        if (node < n) {
            float di = dinv[node];
            float v = acc[dl * 9 + jj] + di * di * h1[(size_t)node * H + j] + bj;
            v = fmaxf(v, 0.0f);
            hout[(size_t)node * H + j] = v;
            sv += v; sq += v * v;
        }
    }
    red[t] = sv; red[256 + t] = sq;
    __syncthreads();
    if (t < 8) {
        float s0 = 0.0f, s1 = 0.0f;
        for (int g2 = 0; g2 < 32; ++g2) { s0 += red[g2 * 8 + t]; s1 += red[256 + g2 * 8 + t]; }
        atomicAdd(&stats[half * 8 + t], s0);
        atomicAdd(&stats[16 + half * 8 + t], s1);
    }
}

// ---------------- BN coefficients ----------------
__global__ void k_bncoef(float* __restrict__ stats, const float* __restrict__ gamma,
                         const float* __restrict__ beta, float nf) {
    int j = threadIdx.x;
    if (j < 16) {
        float mean = stats[j] / nf;
        float var = stats[16 + j] / nf - mean * mean;
        float a = gamma[j] * rsqrtf(var + BN_EPS);
        float c = beta[j] - mean * a;
        stats[j] = a;
        stats[16 + j] = c;
    }
}

// ---------------- BN apply + K_HOPS residual blocks ----------------
__global__ __launch_bounds__(256) void k_hops(float* __restrict__ h,
                                              const float* __restrict__ stats,
                                              const float* __restrict__ Wl,
                                              const float* __restrict__ bl, int n) {
    __shared__ float wl[256], bls[16], av[16], cv[16];
    int t = threadIdx.x;
    wl[t] = Wl[t];
    if (t < 16) { bls[t] = bl[t]; av[t] = stats[t]; cv[t] = stats[16 + t]; }
    __syncthreads();
    int node = blockIdx.x * 256 + t;
    if (node >= n) return;
    float hr[16];
    {
        const float4* hp = reinterpret_cast<const float4*>(h + (size_t)node * H);
        float4 v0 = hp[0], v1 = hp[1], v2 = hp[2], v3 = hp[3];
        hr[0] = v0.x; hr[1] = v0.y; hr[2] = v0.z; hr[3] = v0.w;
        hr[4] = v1.x; hr[5] = v1.y; hr[6] = v1.z; hr[7] = v1.w;
        hr[8] = v2.x; hr[9] = v2.y; hr[10] = v2.z; hr[11] = v2.w;
        hr[12] = v3.x; hr[13] = v3.y; hr[14] = v3.z; hr[15] = v3.w;
    }
#pragma unroll
    for (int j = 0; j < 16; ++j) hr[j] = hr[j] * av[j] + cv[j];
    for (int it = 0; it < K_HOPS; ++it) {
        float tmp[16];
#pragma unroll
        for (int j = 0; j < 16; ++j) {
            float a = bls[j];
#pragma unroll
            for (int k = 0; k < 16; ++k) a = fmaf(hr[k], wl[k * 16 + j], a);
            tmp[j] = fmaxf(a, 0.0f);
        }
#pragma unroll
        for (int j = 0; j < 16; ++j) hr[j] = ALPHA * tmp[j] + (1.0f - ALPHA) * hr[j];
    }
    {
        float4* hp = reinterpret_cast<float4*>(h + (size_t)node * H);
        hp[0] = make_float4(hr[0], hr[1], hr[2], hr[3]);
        hp[1] = make_float4(hr[4], hr[5], hr[6], hr[7]);
        hp[2] = make_float4(hr[8], hr[9], hr[10], hr[11]);
        hp[3] = make_float4(hr[12], hr[13], hr[14], hr[15]);
    }
}

// ---------------- conv2: bucket agg + self-loop ----------------
__global__ __launch_bounds__(256) void k_bagg2(const int* __restrict__ gboff,
                                               const int2* __restrict__ temp,
                                               const float* __restrict__ h,
                                               const float* __restrict__ dinv,
                                               float* __restrict__ agg, int n) {
    __shared__ float acc[RB * 9];
    int t = threadIdx.x;
    int bkt = blockIdx.x >> 1, half = blockIdx.x & 1;
    for (int i = t; i < RB * 9; i += 256) acc[i] = 0.0f;
    __syncthreads();
    bagg_scan(temp, h, gboff[bkt], gboff[bkt + 1], half, acc);
    __syncthreads();
    int jj = t & 7, dgrp = t >> 3;
    int j = half * 8 + jj;
    int node0 = bkt * RB;
#pragma unroll
    for (int k2 = 0; k2 < 16; ++k2) {
        int dl = dgrp + k2 * 32;
        int node = node0 + dl;
        if (node < n) {
            float di = dinv[node];
            agg[(size_t)node * H + j] = acc[dl * 9 + jj] + di * di * h[(size_t)node * H + j];
        }
    }
}

// ---------------- final: agg2 @ W2 + b2 -> log_softmax ----------------
__global__ __launch_bounds__(256) void k_final(const float* __restrict__ agg2,
                                               const float* __restrict__ W2,
                                               const float* __restrict__ b2,
                                               float* __restrict__ out, int n) {
    __shared__ float w2s[16 * 40];
    __shared__ float b2s[40];
    __shared__ float ostage[40 * 257];
    int t = threadIdx.x;
    for (int i = t; i < 640; i += 256) w2s[i] = W2[i];
    if (t < 40) b2s[t] = b2[t];
    __syncthreads();
    int node = blockIdx.x * 256 + t;
    if (node < n) {
        float g[16];
        const float4* ap = reinterpret_cast<const float4*>(agg2 + (size_t)node * H);
#pragma unroll
        for (int r = 0; r < 4; ++r) {
            float4 a = ap[r];
            g[r * 4 + 0] = a.x; g[r * 4 + 1] = a.y; g[r * 4 + 2] = a.z; g[r * 4 + 3] = a.w;
        }
        float z[40];
#pragma unroll
        for (int j = 0; j < 40; ++j) {
            float a = b2s[j];
#pragma unroll
            for (int k = 0; k < 16; ++k) a = fmaf(g[k], w2s[k * 40 + j], a);
            z[j] = a;
        }
        float m = z[0];
#pragma unroll
        for (int j = 1; j < 40; ++j) m = fmaxf(m, z[j]);
        float s = 0.0f;
#pragma unroll
        for (int j = 0; j < 40; ++j) s += expf(z[j] - m);
        float lse = m + logf(s);
#pragma unroll
        for (int j = 0; j < 40; ++j) ostage[j * 257 + t] = z[j] - lse;
    }
    __syncthreads();
    int nodes = n - blockIdx.x * 256;
    if (nodes > 256) nodes = 256;
    int total = nodes * 40;
    size_t base = (size_t)blockIdx.x * 256 * 40;
    for (int i = t; i < total; i += 256) {
        int nl = i / 40;
        int j = i - nl * 40;
        out[base + i] = ostage[j * 257 + nl];
    }
}

extern "C" void kernel_launch(void* const* d_in, const int* in_sizes, int n_in,
                              void* d_out, int out_size, void* d_ws, size_t ws_size,
                              hipStream_t stream) {
    const float* x     = (const float*)d_in[0];
    const int*   src   = (const int*)d_in[1];
    const int*   dst   = (const int*)d_in[2];
    const float* W1    = (const float*)d_in[3];
    const float* b1    = (const float*)d_in[4];
    const float* gamma = (const float*)d_in[5];
    const float* beta  = (const float*)d_in[6];
    const float* Wl    = (const float*)d_in[7];
    const float* bl    = (const float*)d_in[8];
    const float* W2    = (const float*)d_in[9];
    const float* b2    = (const float*)d_in[10];
    float* out = (float*)d_out;

    int n = in_sizes[0] / F_IN;   // 100000
    int e = in_sizes[1];          // 3200000
    int nbkt = (n + RB - 1) >> RB_BITS;   // 196
    int nAlign = (n + 7) & ~7;

    char* wsb = (char*)d_ws;
    int2*  temp   = (int2*)wsb;       wsb += (size_t)e * 8;          // 8B-aligned first
    int*   cnt    = (int*)wsb;        wsb += (size_t)nAlign * 4;
    float* dinv   = (float*)wsb;      wsb += (size_t)nAlign * 4;
    int*   gbcnt  = (int*)wsb;        wsb += NBKT_MAX * 4;
    int*   gboff  = (int*)wsb;        wsb += (NBKT_MAX + 8) * 4;
    int*   gcur   = (int*)wsb;        wsb += NBKT_MAX * 4;
    float* stats  = (float*)wsb;      wsb += 64 * 4;
    float* h1     = (float*)wsb;      wsb += (size_t)nAlign * H * 4;
    float* hbuf   = (float*)wsb;      wsb += (size_t)nAlign * H * 4;
    float* agg2   = (float*)wsb;      wsb += (size_t)nAlign * H * 4;

    int nbE = (e + 4095) / 4096;   // 782

    k_zero<<<391, 256, 0, stream>>>(cnt, gbcnt, stats, n);
    k_degbk<<<nbE, 256, 0, stream>>>(dst, cnt, gbcnt, e);
    k_dinv<<<(n + 255) / 256, 256, 0, stream>>>(cnt, dinv, n);
    k_bscan<<<1, 256, 0, stream>>>(gbcnt, gboff, gcur, nbkt);
    k_bin<<<(e + BIN_CHUNK - 1) / BIN_CHUNK, 256, 0, stream>>>(src, dst, dinv, gcur, temp, e);
    k_mm1<<<(n + 15) / 16, 256, 0, stream>>>(x, W1, h1, n);
    k_bagg1<<<nbkt * 2, 256, 0, stream>>>(gboff, temp, h1, dinv, b1, hbuf, stats, n);
    k_bncoef<<<1, 16, 0, stream>>>(stats, gamma, beta, (float)n);
    k_hops<<<(n + 255) / 256, 256, 0, stream>>>(hbuf, stats, Wl, bl, n);
    k_bagg2<<<nbkt * 2, 256, 0, stream>>>(gboff, temp, hbuf, dinv, agg2, n);
    k_final<<<(n + 255) / 256, 256, 0, stream>>>(agg2, W2, b2, out, n);
}

// Round 4
// 425.076 us; speedup vs baseline: 2.5025x; 2.5025x over previous
//
#include <hip/hip_runtime.h>
#include <hip/hip_fp16.h>
#include <math.h>

#define F_IN 128
#define H 16
#define C 40
#define K_HOPS 10
#define ALPHA 0.1f
#define BN_EPS 1e-5f

#define RB 512          // nodes per bucket
#define RB_BITS 9
#define NBKT_MAX 256    // ceil(100000/512)=196
#define SRC_MASK 0x1FFFF

// ---------------- zero: gbcnt=0, stats=0 ----------------
__global__ void k_zero(int* __restrict__ gbcnt, float* __restrict__ stats) {
    int id = blockIdx.x * blockDim.x + threadIdx.x;
    if (id < NBKT_MAX) gbcnt[id] = 0;
    if (id < 32) stats[id] = 0.0f;
}

// ---------------- bucket counts ----------------
__global__ __launch_bounds__(256) void k_bcnt(const int* __restrict__ dst,
                                              int* __restrict__ gbcnt, int e) {
    __shared__ int hist[NBKT_MAX];
    int t = threadIdx.x;
    if (t < NBKT_MAX) hist[t] = 0;
    __syncthreads();
    int base = blockIdx.x * 4096;
    int endi = base + 4096; if (endi > e) endi = e;
    for (int i = base + t; i < endi; i += 256)
        atomicAdd(&hist[dst[i] >> RB_BITS], 1);
    __syncthreads();
    if (t < NBKT_MAX && hist[t]) atomicAdd(&gbcnt[t], hist[t]);
}

// ---------------- exclusive scan of bucket counts (single block) ----------------
__global__ __launch_bounds__(256) void k_bscan(const int* __restrict__ gbcnt,
                                               int* __restrict__ gboff,
                                               int* __restrict__ gcur,
                                               int* __restrict__ nodeoff,
                                               int nbkt, int n) {
    __shared__ int sd[256];
    int t = threadIdx.x;
    int v = (t < nbkt) ? gbcnt[t] : 0;
    sd[t] = v;
    __syncthreads();
    for (int off = 1; off < 256; off <<= 1) {
        int tmp = (t >= off) ? sd[t - off] : 0;
        __syncthreads();
        sd[t] += tmp;
        __syncthreads();
    }
    if (t < nbkt) { int o = sd[t] - v; gboff[t] = o; gcur[t] = o; }
    if (t == nbkt - 1) { gboff[nbkt] = sd[t]; nodeoff[n] = sd[t]; }
}

// ---------------- bin edges into bucket runs (dense 4B writes) ----------------
#define BIN_CHUNK 4096
__global__ __launch_bounds__(256) void k_bin(const int* __restrict__ src,
                                             const int* __restrict__ dst,
                                             int* __restrict__ gcur,
                                             int* __restrict__ temp, int e) {
    __shared__ int hist[NBKT_MAX];
    __shared__ int lcur[NBKT_MAX];
    int t = threadIdx.x;
    if (t < NBKT_MAX) hist[t] = 0;
    __syncthreads();
    int base = blockIdx.x * BIN_CHUNK;
    int ss[16], dd[16];
#pragma unroll
    for (int i = 0; i < 16; ++i) {
        int idx = base + i * 256 + t;
        if (idx < e) {
            ss[i] = src[idx]; dd[i] = dst[idx];
            atomicAdd(&hist[dd[i] >> RB_BITS], 1);
        } else ss[i] = -1;
    }
    __syncthreads();
    if (t < NBKT_MAX) {
        int h = hist[t];
        lcur[t] = h ? atomicAdd(&gcur[t], h) : 0;
    }
    __syncthreads();
#pragma unroll
    for (int i = 0; i < 16; ++i) {
        if (ss[i] >= 0) {
            int d = dd[i];
            int b = d >> RB_BITS;
            int pos = atomicAdd(&lcur[b], 1);
            temp[pos] = ss[i] | ((d & (RB - 1)) << 17);
        }
    }
}

// ---------------- per-bucket counting sort -> CSR; also deg->dinv, nodeoff ----------------
__global__ __launch_bounds__(256) void k_sort(const int* __restrict__ gboff,
                                              const int* __restrict__ temp,
                                              int* __restrict__ csr,
                                              int* __restrict__ nodeoff,
                                              float* __restrict__ dinv, int n) {
    __shared__ int hist[RB];
    __shared__ int psum[256];
    int t = threadIdx.x;
    int bkt = blockIdx.x;
    int start = gboff[bkt], endi = gboff[bkt + 1];
    hist[t] = 0; hist[t + 256] = 0;
    __syncthreads();
    for (int k = start + t; k < endi; k += 256)
        atomicAdd(&hist[temp[k] >> 17], 1);
    __syncthreads();
    int node0 = bkt * RB;
    int h0 = hist[2 * t], h1v = hist[2 * t + 1];
    if (node0 + 2 * t     < n) dinv[node0 + 2 * t]     = rsqrtf((float)(h0 + 1));
    if (node0 + 2 * t + 1 < n) dinv[node0 + 2 * t + 1] = rsqrtf((float)(h1v + 1));
    psum[t] = h0 + h1v;
    __syncthreads();
    for (int off = 1; off < 256; off <<= 1) {
        int tmp = (t >= off) ? psum[t - off] : 0;
        __syncthreads();
        psum[t] += tmp;
        __syncthreads();
    }
    int pexcl = psum[t] - (h0 + h1v);
    int off0 = pexcl, off1 = pexcl + h0;
    if (node0 + 2 * t     < n) nodeoff[node0 + 2 * t]     = start + off0;
    if (node0 + 2 * t + 1 < n) nodeoff[node0 + 2 * t + 1] = start + off1;
    // reuse hist as scatter cursors
    hist[2 * t] = off0; hist[2 * t + 1] = off1;
    __syncthreads();
    for (int k = start + t; k < endi; k += 256) {
        int v = temp[k];
        int dl = v >> 17;
        int pos = start + atomicAdd(&hist[dl], 1);
        csr[pos] = v & SRC_MASK;
    }
}

// ---------------- h1 = x @ W1 -> fp16 table ----------------
__global__ __launch_bounds__(256) void k_mm1(const float* __restrict__ x,
                                             const float* __restrict__ W1,
                                             __half* __restrict__ h1h, int n) {
    __shared__ float xs[16 * 132];
    __shared__ float ws[128 * 16];
    int t = threadIdx.x;
    int node0 = blockIdx.x * 16;
#pragma unroll
    for (int r = 0; r < 8; ++r) {
        int idx = t + r * 256;
        int nl = idx >> 7, k = idx & 127;
        int nn = node0 + nl; if (nn >= n) nn = n - 1;
        xs[nl * 132 + k] = x[(size_t)nn * F_IN + k];
        ws[idx] = W1[idx];
    }
    __syncthreads();
    int nl = t >> 4, j = t & 15;
    float acc = 0.0f;
#pragma unroll 8
    for (int k = 0; k < 128; ++k)
        acc = fmaf(xs[nl * 132 + k], ws[k * 16 + j], acc);
    int node = node0 + nl;
    if (node < n) h1h[(size_t)node * H + j] = __float2half(acc);
}

// ---------------- gather conv1 (fp16 table): agg + self + bias + ReLU + BN stats ----------------
__global__ __launch_bounds__(256) void k_gather1(const int* __restrict__ nodeoff,
                                                 const int* __restrict__ csr,
                                                 const __half* __restrict__ h1h,
                                                 const float* __restrict__ dinv,
                                                 const float* __restrict__ b1,
                                                 float* __restrict__ hout,
                                                 float* __restrict__ stats, int n) {
    __shared__ float sv[256], sq[256];
    int t = threadIdx.x;
    int idx = blockIdx.x * 256 + t;
    int node = idx >> 4, j = idx & 15;
    float v = 0.0f;
    if (node < n) {
        int k = nodeoff[node], endi = nodeoff[node + 1];
        float din = dinv[node];
        float acc = 0.0f;
        for (; k + 1 < endi; k += 2) {
            int s0 = csr[k], s1 = csr[k + 1];
            float w0 = dinv[s0] * din, w1 = dinv[s1] * din;
            float v0 = __half2float(h1h[(size_t)s0 * H + j]);
            float v1 = __half2float(h1h[(size_t)s1 * H + j]);
            acc = fmaf(v0, w0, acc);
            acc = fmaf(v1, w1, acc);
        }
        if (k < endi) {
            int s0 = csr[k];
            acc = fmaf(__half2float(h1h[(size_t)s0 * H + j]), dinv[s0] * din, acc);
        }
        v = acc + din * din * __half2float(h1h[(size_t)node * H + j]) + b1[j];
        v = fmaxf(v, 0.0f);
        hout[idx] = v;
    }
    sv[t] = v; sq[t] = v * v;
    __syncthreads();
    if (t < 16) {
        float s0 = 0.0f, s1 = 0.0f;
#pragma unroll
        for (int r = 0; r < 16; ++r) { s0 += sv[r * 16 + t]; s1 += sq[r * 16 + t]; }
        atomicAdd(&stats[t], s0);
        atomicAdd(&stats[16 + t], s1);
    }
}

// ---------------- BN coefficients ----------------
__global__ void k_bncoef(float* __restrict__ stats, const float* __restrict__ gamma,
                         const float* __restrict__ beta, float nf) {
    int j = threadIdx.x;
    if (j < 16) {
        float mean = stats[j] / nf;
        float var = stats[16 + j] / nf - mean * mean;
        float a = gamma[j] * rsqrtf(var + BN_EPS);
        float c = beta[j] - mean * a;
        stats[j] = a;
        stats[16 + j] = c;
    }
}

// ---------------- BN apply + K_HOPS residual blocks -> fp16 table ----------------
__global__ __launch_bounds__(256) void k_hops(const float* __restrict__ h,
                                              __half* __restrict__ hh,
                                              const float* __restrict__ stats,
                                              const float* __restrict__ Wl,
                                              const float* __restrict__ bl, int n) {
    __shared__ float wl[256], bls[16], av[16], cv[16];
    int t = threadIdx.x;
    wl[t] = Wl[t];
    if (t < 16) { bls[t] = bl[t]; av[t] = stats[t]; cv[t] = stats[16 + t]; }
    __syncthreads();
    int node = blockIdx.x * 256 + t;
    if (node >= n) return;
    float hr[16];
    {
        const float4* hp = reinterpret_cast<const float4*>(h + (size_t)node * H);
        float4 v0 = hp[0], v1 = hp[1], v2 = hp[2], v3 = hp[3];
        hr[0] = v0.x; hr[1] = v0.y; hr[2] = v0.z; hr[3] = v0.w;
        hr[4] = v1.x; hr[5] = v1.y; hr[6] = v1.z; hr[7] = v1.w;
        hr[8] = v2.x; hr[9] = v2.y; hr[10] = v2.z; hr[11] = v2.w;
        hr[12] = v3.x; hr[13] = v3.y; hr[14] = v3.z; hr[15] = v3.w;
    }
#pragma unroll
    for (int j = 0; j < 16; ++j) hr[j] = hr[j] * av[j] + cv[j];
    for (int it = 0; it < K_HOPS; ++it) {
        float tmp[16];
#pragma unroll
        for (int j = 0; j < 16; ++j) {
            float a = bls[j];
#pragma unroll
            for (int k = 0; k < 16; ++k) a = fmaf(hr[k], wl[k * 16 + j], a);
            tmp[j] = fmaxf(a, 0.0f);
        }
#pragma unroll
        for (int j = 0; j < 16; ++j) hr[j] = ALPHA * tmp[j] + (1.0f - ALPHA) * hr[j];
    }
    {
        __half2 ph[8];
#pragma unroll
        for (int i = 0; i < 8; ++i) ph[i] = __floats2half2_rn(hr[2 * i], hr[2 * i + 1]);
        int4* hp = reinterpret_cast<int4*>(hh + (size_t)node * H);
        hp[0] = *reinterpret_cast<int4*>(&ph[0]);
        hp[1] = *reinterpret_cast<int4*>(&ph[4]);
    }
}

// ---------------- gather conv2 (fp16 table): agg + self-loop ----------------
__global__ __launch_bounds__(256) void k_gather2(const int* __restrict__ nodeoff,
                                                 const int* __restrict__ csr,
                                                 const __half* __restrict__ hh,
                                                 const float* __restrict__ dinv,
                                                 float* __restrict__ agg, int n) {
    int idx = blockIdx.x * 256 + threadIdx.x;
    int node = idx >> 4, j = idx & 15;
    if (node >= n) return;
    int k = nodeoff[node], endi = nodeoff[node + 1];
    float din = dinv[node];
    float acc = 0.0f;
    for (; k + 1 < endi; k += 2) {
        int s0 = csr[k], s1 = csr[k + 1];
        float w0 = dinv[s0] * din, w1 = dinv[s1] * din;
        float v0 = __half2float(hh[(size_t)s0 * H + j]);
        float v1 = __half2float(hh[(size_t)s1 * H + j]);
        acc = fmaf(v0, w0, acc);
        acc = fmaf(v1, w1, acc);
    }
    if (k < endi) {
        int s0 = csr[k];
        acc = fmaf(__half2float(hh[(size_t)s0 * H + j]), dinv[s0] * din, acc);
    }
    agg[idx] = acc + din * din * __half2float(hh[(size_t)node * H + j]);
}

// ---------------- final: agg2 @ W2 + b2 -> log_softmax ----------------
__global__ __launch_bounds__(256) void k_final(const float* __restrict__ agg2,
                                               const float* __restrict__ W2,
                                               const float* __restrict__ b2,
                                               float* __restrict__ out, int n) {
    __shared__ float w2s[16 * 40];
    __shared__ float b2s[40];
    __shared__ float ostage[40 * 257];
    int t = threadIdx.x;
    for (int i = t; i < 640; i += 256) w2s[i] = W2[i];
    if (t < 40) b2s[t] = b2[t];
    __syncthreads();
    int node = blockIdx.x * 256 + t;
    if (node < n) {
        float g[16];
        const float4* ap = reinterpret_cast<const float4*>(agg2 + (size_t)node * H);
#pragma unroll
        for (int r = 0; r < 4; ++r) {
            float4 a = ap[r];
            g[r * 4 + 0] = a.x; g[r * 4 + 1] = a.y; g[r * 4 + 2] = a.z; g[r * 4 + 3] = a.w;
        }
        float z[40];
#pragma unroll
        for (int j = 0; j < 40; ++j) {
            float a = b2s[j];
#pragma unroll
            for (int k = 0; k < 16; ++k) a = fmaf(g[k], w2s[k * 40 + j], a);
            z[j] = a;
        }
        float m = z[0];
#pragma unroll
        for (int j = 1; j < 40; ++j) m = fmaxf(m, z[j]);
        float s = 0.0f;
#pragma unroll
        for (int j = 0; j < 40; ++j) s += expf(z[j] - m);
        float lse = m + logf(s);
#pragma unroll
        for (int j = 0; j < 40; ++j) ostage[j * 257 + t] = z[j] - lse;
    }
    __syncthreads();
    int nodes = n - blockIdx.x * 256;
    if (nodes > 256) nodes = 256;
    int total = nodes * 40;
    size_t base = (size_t)blockIdx.x * 256 * 40;
    for (int i = t; i < total; i += 256) {
        int nl = i / 40;
        int j = i - nl * 40;
        out[base + i] = ostage[j * 257 + nl];
    }
}

extern "C" void kernel_launch(void* const* d_in, const int* in_sizes, int n_in,
                              void* d_out, int out_size, void* d_ws, size_t ws_size,
                              hipStream_t stream) {
    const float* x     = (const float*)d_in[0];
    const int*   src   = (const int*)d_in[1];
    const int*   dst   = (const int*)d_in[2];
    const float* W1    = (const float*)d_in[3];
    const float* b1    = (const float*)d_in[4];
    const float* gamma = (const float*)d_in[5];
    const float* beta  = (const float*)d_in[6];
    const float* Wl    = (const float*)d_in[7];
    const float* bl    = (const float*)d_in[8];
    const float* W2    = (const float*)d_in[9];
    const float* b2    = (const float*)d_in[10];
    float* out = (float*)d_out;

    int n = in_sizes[0] / F_IN;   // 100000
    int e = in_sizes[1];          // 3200000
    int nbkt = (n + RB - 1) >> RB_BITS;   // 196
    int nAlign = (n + 15) & ~15;

    char* wsb = (char*)d_ws;
    int*    temp    = (int*)wsb;      wsb += (size_t)e * 4;
    int*    csr     = (int*)wsb;      wsb += (size_t)e * 4;
    int*    nodeoff = (int*)wsb;      wsb += (size_t)(nAlign + 16) * 4;
    float*  dinv    = (float*)wsb;    wsb += (size_t)nAlign * 4;
    int*    gbcnt   = (int*)wsb;      wsb += NBKT_MAX * 4;
    int*    gboff   = (int*)wsb;      wsb += (NBKT_MAX + 16) * 4;
    int*    gcur    = (int*)wsb;      wsb += NBKT_MAX * 4;
    float*  stats   = (float*)wsb;    wsb += 64 * 4;
    __half* h1h     = (__half*)wsb;   wsb += (size_t)nAlign * H * 2;
    __half* hh      = (__half*)wsb;   wsb += (size_t)nAlign * H * 2;
    float*  hbuf    = (float*)wsb;    wsb += (size_t)nAlign * H * 4;
    float*  agg2    = (float*)wsb;    wsb += (size_t)nAlign * H * 4;

    int nbE = (e + 4095) / 4096;   // 782

    k_zero<<<1, 256, 0, stream>>>(gbcnt, stats);
    k_bcnt<<<nbE, 256, 0, stream>>>(dst, gbcnt, e);
    k_bscan<<<1, 256, 0, stream>>>(gbcnt, gboff, gcur, nodeoff, nbkt, n);
    k_bin<<<(e + BIN_CHUNK - 1) / BIN_CHUNK, 256, 0, stream>>>(src, dst, gcur, temp, e);
    k_sort<<<nbkt, 256, 0, stream>>>(gboff, temp, csr, nodeoff, dinv, n);
    k_mm1<<<(n + 15) / 16, 256, 0, stream>>>(x, W1, h1h, n);
    k_gather1<<<(n * 16 + 255) / 256, 256, 0, stream>>>(nodeoff, csr, h1h, dinv, b1, hbuf, stats, n);
    k_bncoef<<<1, 16, 0, stream>>>(stats, gamma, beta, (float)n);
    k_hops<<<(n + 255) / 256, 256, 0, stream>>>(hbuf, hh, stats, Wl, bl, n);
    k_gather2<<<(n * 16 + 255) / 256, 256, 0, stream>>>(nodeoff, csr, hh, dinv, agg2, n);
    k_final<<<(n + 255) / 256, 256, 0, stream>>>(agg2, W2, b2, out, n);
}

// Round 5
// 384.913 us; speedup vs baseline: 2.7636x; 1.1043x over previous
//
#include <hip/hip_runtime.h>
#include <hip/hip_fp16.h>
#include <math.h>

#define F_IN 128
#define H 16
#define C 40
#define K_HOPS 10
#define ALPHA 0.1f
#define BN_EPS 1e-5f

#define RB 512          // nodes per bucket
#define RB_BITS 9
#define NBKT_MAX 256    // ceil(100000/512)=196
#define SRC_MASK 0x1FFFF

// ---------------- zero: gbcnt=0, stats=0 ----------------
__global__ void k_zero(int* __restrict__ gbcnt, float* __restrict__ stats) {
    int id = blockIdx.x * blockDim.x + threadIdx.x;
    if (id < NBKT_MAX) gbcnt[id] = 0;
    if (id < 32) stats[id] = 0.0f;
}

// ---------------- bucket counts ----------------
__global__ __launch_bounds__(256) void k_bcnt(const int* __restrict__ dst,
                                              int* __restrict__ gbcnt, int e) {
    __shared__ int hist[NBKT_MAX];
    int t = threadIdx.x;
    if (t < NBKT_MAX) hist[t] = 0;
    __syncthreads();
    int base = blockIdx.x * 4096;
    int endi = base + 4096; if (endi > e) endi = e;
    for (int i = base + t; i < endi; i += 256)
        atomicAdd(&hist[dst[i] >> RB_BITS], 1);
    __syncthreads();
    if (t < NBKT_MAX && hist[t]) atomicAdd(&gbcnt[t], hist[t]);
}

// ---------------- exclusive scan of bucket counts (single block) ----------------
__global__ __launch_bounds__(256) void k_bscan(const int* __restrict__ gbcnt,
                                               int* __restrict__ gboff,
                                               int* __restrict__ gcur,
                                               int* __restrict__ nodeoff,
                                               int nbkt, int n) {
    __shared__ int sd[256];
    int t = threadIdx.x;
    int v = (t < nbkt) ? gbcnt[t] : 0;
    sd[t] = v;
    __syncthreads();
    for (int off = 1; off < 256; off <<= 1) {
        int tmp = (t >= off) ? sd[t - off] : 0;
        __syncthreads();
        sd[t] += tmp;
        __syncthreads();
    }
    if (t < nbkt) { int o = sd[t] - v; gboff[t] = o; gcur[t] = o; }
    if (t == nbkt - 1) { gboff[nbkt] = sd[t]; nodeoff[n] = sd[t]; }
}

// ---------------- bin edges into bucket runs (dense 4B writes) ----------------
#define BIN_CHUNK 4096
__global__ __launch_bounds__(256) void k_bin(const int* __restrict__ src,
                                             const int* __restrict__ dst,
                                             int* __restrict__ gcur,
                                             int* __restrict__ temp, int e) {
    __shared__ int hist[NBKT_MAX];
    __shared__ int lcur[NBKT_MAX];
    int t = threadIdx.x;
    if (t < NBKT_MAX) hist[t] = 0;
    __syncthreads();
    int base = blockIdx.x * BIN_CHUNK;
    int ss[16], dd[16];
#pragma unroll
    for (int i = 0; i < 16; ++i) {
        int idx = base + i * 256 + t;
        if (idx < e) {
            ss[i] = src[idx]; dd[i] = dst[idx];
            atomicAdd(&hist[dd[i] >> RB_BITS], 1);
        } else ss[i] = -1;
    }
    __syncthreads();
    if (t < NBKT_MAX) {
        int h = hist[t];
        lcur[t] = h ? atomicAdd(&gcur[t], h) : 0;
    }
    __syncthreads();
#pragma unroll
    for (int i = 0; i < 16; ++i) {
        if (ss[i] >= 0) {
            int d = dd[i];
            int b = d >> RB_BITS;
            int pos = atomicAdd(&lcur[b], 1);
            temp[pos] = ss[i] | ((d & (RB - 1)) << 17);
        }
    }
}

// ---------------- per-bucket counting sort -> CSR (src only); deg->dinv, nodeoff ----------------
__global__ __launch_bounds__(256) void k_sort(const int* __restrict__ gboff,
                                              const int* __restrict__ temp,
                                              int* __restrict__ csr,
                                              int* __restrict__ nodeoff,
                                              float* __restrict__ dinv, int n) {
    __shared__ int hist[RB];
    __shared__ int psum[256];
    int t = threadIdx.x;
    int bkt = blockIdx.x;
    int start = gboff[bkt], endi = gboff[bkt + 1];
    hist[t] = 0; hist[t + 256] = 0;
    __syncthreads();
    for (int k = start + t; k < endi; k += 256)
        atomicAdd(&hist[temp[k] >> 17], 1);
    __syncthreads();
    int node0 = bkt * RB;
    int h0 = hist[2 * t], h1v = hist[2 * t + 1];
    if (node0 + 2 * t     < n) dinv[node0 + 2 * t]     = rsqrtf((float)(h0 + 1));
    if (node0 + 2 * t + 1 < n) dinv[node0 + 2 * t + 1] = rsqrtf((float)(h1v + 1));
    psum[t] = h0 + h1v;
    __syncthreads();
    for (int off = 1; off < 256; off <<= 1) {
        int tmp = (t >= off) ? psum[t - off] : 0;
        __syncthreads();
        psum[t] += tmp;
        __syncthreads();
    }
    int pexcl = psum[t] - (h0 + h1v);
    int off0 = pexcl, off1 = pexcl + h0;
    if (node0 + 2 * t     < n) nodeoff[node0 + 2 * t]     = start + off0;
    if (node0 + 2 * t + 1 < n) nodeoff[node0 + 2 * t + 1] = start + off1;
    hist[2 * t] = off0; hist[2 * t + 1] = off1;
    __syncthreads();
    for (int k = start + t; k < endi; k += 256) {
        int v = temp[k];
        int dl = v >> 17;
        int pos = start + atomicAdd(&hist[dl], 1);
        csr[pos] = v & SRC_MASK;
    }
}

// ---------------- h1' = dinv .* (x @ W1) -> fp16 table ----------------
__global__ __launch_bounds__(256) void k_mm1(const float* __restrict__ x,
                                             const float* __restrict__ W1,
                                             const float* __restrict__ dinv,
                                             __half* __restrict__ h1h, int n) {
    __shared__ float xs[16 * 132];
    __shared__ float ws[128 * 16];
    int t = threadIdx.x;
    int node0 = blockIdx.x * 16;
#pragma unroll
    for (int r = 0; r < 8; ++r) {
        int idx = t + r * 256;
        int nl = idx >> 7, k = idx & 127;
        int nn = node0 + nl; if (nn >= n) nn = n - 1;
        xs[nl * 132 + k] = x[(size_t)nn * F_IN + k];
        ws[idx] = W1[idx];
    }
    __syncthreads();
    int nl = t >> 4, j = t & 15;
    float acc = 0.0f;
#pragma unroll 8
    for (int k = 0; k < 128; ++k)
        acc = fmaf(xs[nl * 132 + k], ws[k * 16 + j], acc);
    int node = node0 + nl;
    if (node < n) h1h[(size_t)node * H + j] = __float2half(acc * dinv[node]);
}

// ---------------- gather conv1: 8 lanes/node, half2, unroll 4; + bias + ReLU + BN stats ----------------
__global__ __launch_bounds__(256) void k_gather1(const int* __restrict__ nodeoff,
                                                 const int* __restrict__ csr,
                                                 const __half* __restrict__ h1h,
                                                 const float* __restrict__ dinv,
                                                 const float* __restrict__ b1,
                                                 float* __restrict__ hout,
                                                 float* __restrict__ stats, int n) {
    __shared__ float red[4][256];
    int t = threadIdx.x;
    int idx = blockIdx.x * 256 + t;
    int node = idx >> 3, jj = idx & 7;
    float ax = 0.0f, ay = 0.0f, vx = 0.0f, vy = 0.0f;
    if (node < n) {
        int k = nodeoff[node], endi = nodeoff[node + 1];
        const __half2* h2 = reinterpret_cast<const __half2*>(h1h);
        for (; k + 3 < endi; k += 4) {
            int s0 = csr[k], s1 = csr[k + 1], s2 = csr[k + 2], s3 = csr[k + 3];
            __half2 g0 = h2[(size_t)s0 * 8 + jj];
            __half2 g1 = h2[(size_t)s1 * 8 + jj];
            __half2 g2 = h2[(size_t)s2 * 8 + jj];
            __half2 g3 = h2[(size_t)s3 * 8 + jj];
            float2 f0 = __half22float2(g0), f1 = __half22float2(g1);
            float2 f2 = __half22float2(g2), f3 = __half22float2(g3);
            ax += (f0.x + f1.x) + (f2.x + f3.x);
            ay += (f0.y + f1.y) + (f2.y + f3.y);
        }
        for (; k < endi; ++k) {
            int s = csr[k];
            float2 f = __half22float2(h2[(size_t)s * 8 + jj]);
            ax += f.x; ay += f.y;
        }
        float din = dinv[node];
        float2 self = __half22float2(h2[(size_t)node * 8 + jj]);
        vx = fmaxf(din * (ax + self.x) + b1[2 * jj], 0.0f);
        vy = fmaxf(din * (ay + self.y) + b1[2 * jj + 1], 0.0f);
        reinterpret_cast<float2*>(hout)[(size_t)node * 8 + jj] = make_float2(vx, vy);
    }
    red[0][t] = vx; red[1][t] = vy; red[2][t] = vx * vx; red[3][t] = vy * vy;
    __syncthreads();
    if (t < 8) {
        float s0 = 0.0f, s1 = 0.0f, s2 = 0.0f, s3 = 0.0f;
        for (int g = 0; g < 32; ++g) {
            int i = g * 8 + t;
            s0 += red[0][i]; s1 += red[1][i]; s2 += red[2][i]; s3 += red[3][i];
        }
        atomicAdd(&stats[2 * t], s0);
        atomicAdd(&stats[2 * t + 1], s1);
        atomicAdd(&stats[16 + 2 * t], s2);
        atomicAdd(&stats[16 + 2 * t + 1], s3);
    }
}

// ---------------- BN coefficients ----------------
__global__ void k_bncoef(float* __restrict__ stats, const float* __restrict__ gamma,
                         const float* __restrict__ beta, float nf) {
    int j = threadIdx.x;
    if (j < 16) {
        float mean = stats[j] / nf;
        float var = stats[16 + j] / nf - mean * mean;
        float a = gamma[j] * rsqrtf(var + BN_EPS);
        float c = beta[j] - mean * a;
        stats[j] = a;
        stats[16 + j] = c;
    }
}

// ---------------- BN apply + K_HOPS residual blocks -> scaled fp16 table ----------------
__global__ __launch_bounds__(256) void k_hops(const float* __restrict__ h,
                                              __half* __restrict__ hh,
                                              const float* __restrict__ stats,
                                              const float* __restrict__ Wl,
                                              const float* __restrict__ bl,
                                              const float* __restrict__ dinv, int n) {
    __shared__ float wl[256], bls[16], av[16], cv[16];
    int t = threadIdx.x;
    wl[t] = Wl[t];
    if (t < 16) { bls[t] = bl[t]; av[t] = stats[t]; cv[t] = stats[16 + t]; }
    __syncthreads();
    int node = blockIdx.x * 256 + t;
    if (node >= n) return;
    float hr[16];
    {
        const float4* hp = reinterpret_cast<const float4*>(h + (size_t)node * H);
        float4 v0 = hp[0], v1 = hp[1], v2 = hp[2], v3 = hp[3];
        hr[0] = v0.x; hr[1] = v0.y; hr[2] = v0.z; hr[3] = v0.w;
        hr[4] = v1.x; hr[5] = v1.y; hr[6] = v1.z; hr[7] = v1.w;
        hr[8] = v2.x; hr[9] = v2.y; hr[10] = v2.z; hr[11] = v2.w;
        hr[12] = v3.x; hr[13] = v3.y; hr[14] = v3.z; hr[15] = v3.w;
    }
#pragma unroll
    for (int j = 0; j < 16; ++j) hr[j] = hr[j] * av[j] + cv[j];
    for (int it = 0; it < K_HOPS; ++it) {
        float tmp[16];
#pragma unroll
        for (int j = 0; j < 16; ++j) {
            float a = bls[j];
#pragma unroll
            for (int k = 0; k < 16; ++k) a = fmaf(hr[k], wl[k * 16 + j], a);
            tmp[j] = fmaxf(a, 0.0f);
        }
#pragma unroll
        for (int j = 0; j < 16; ++j) hr[j] = ALPHA * tmp[j] + (1.0f - ALPHA) * hr[j];
    }
    {
        float din = dinv[node];
        __half2 ph[8];
#pragma unroll
        for (int i = 0; i < 8; ++i)
            ph[i] = __floats2half2_rn(hr[2 * i] * din, hr[2 * i + 1] * din);
        int4* hp = reinterpret_cast<int4*>(hh + (size_t)node * H);
        hp[0] = *reinterpret_cast<int4*>(&ph[0]);
        hp[1] = *reinterpret_cast<int4*>(&ph[4]);
    }
}

// ---------------- gather conv2: 8 lanes/node, half2, unroll 4; + self-loop ----------------
__global__ __launch_bounds__(256) void k_gather2(const int* __restrict__ nodeoff,
                                                 const int* __restrict__ csr,
                                                 const __half* __restrict__ hh,
                                                 const float* __restrict__ dinv,
                                                 float* __restrict__ agg, int n) {
    int idx = blockIdx.x * 256 + threadIdx.x;
    int node = idx >> 3, jj = idx & 7;
    if (node >= n) return;
    int k = nodeoff[node], endi = nodeoff[node + 1];
    const __half2* h2 = reinterpret_cast<const __half2*>(hh);
    float ax = 0.0f, ay = 0.0f;
    for (; k + 3 < endi; k += 4) {
        int s0 = csr[k], s1 = csr[k + 1], s2 = csr[k + 2], s3 = csr[k + 3];
        __half2 g0 = h2[(size_t)s0 * 8 + jj];
        __half2 g1 = h2[(size_t)s1 * 8 + jj];
        __half2 g2 = h2[(size_t)s2 * 8 + jj];
        __half2 g3 = h2[(size_t)s3 * 8 + jj];
        float2 f0 = __half22float2(g0), f1 = __half22float2(g1);
        float2 f2 = __half22float2(g2), f3 = __half22float2(g3);
        ax += (f0.x + f1.x) + (f2.x + f3.x);
        ay += (f0.y + f1.y) + (f2.y + f3.y);
    }
    for (; k < endi; ++k) {
        int s = csr[k];
        float2 f = __half22float2(h2[(size_t)s * 8 + jj]);
        ax += f.x; ay += f.y;
    }
    float din = dinv[node];
    float2 self = __half22float2(h2[(size_t)node * 8 + jj]);
    reinterpret_cast<float2*>(agg)[(size_t)node * 8 + jj] =
        make_float2(din * (ax + self.x), din * (ay + self.y));
}

// ---------------- final: agg2 @ W2 + b2 -> log_softmax ----------------
__global__ __launch_bounds__(256) void k_final(const float* __restrict__ agg2,
                                               const float* __restrict__ W2,
                                               const float* __restrict__ b2,
                                               float* __restrict__ out, int n) {
    __shared__ float w2s[16 * 40];
    __shared__ float b2s[40];
    __shared__ float ostage[40 * 257];
    int t = threadIdx.x;
    for (int i = t; i < 640; i += 256) w2s[i] = W2[i];
    if (t < 40) b2s[t] = b2[t];
    __syncthreads();
    int node = blockIdx.x * 256 + t;
    if (node < n) {
        float g[16];
        const float4* ap = reinterpret_cast<const float4*>(agg2 + (size_t)node * H);
#pragma unroll
        for (int r = 0; r < 4; ++r) {
            float4 a = ap[r];
            g[r * 4 + 0] = a.x; g[r * 4 + 1] = a.y; g[r * 4 + 2] = a.z; g[r * 4 + 3] = a.w;
        }
        float z[40];
#pragma unroll
        for (int j = 0; j < 40; ++j) {
            float a = b2s[j];
#pragma unroll
            for (int k = 0; k < 16; ++k) a = fmaf(g[k], w2s[k * 40 + j], a);
            z[j] = a;
        }
        float m = z[0];
#pragma unroll
        for (int j = 1; j < 40; ++j) m = fmaxf(m, z[j]);
        float s = 0.0f;
#pragma unroll
        for (int j = 0; j < 40; ++j) s += expf(z[j] - m);
        float lse = m + logf(s);
#pragma unroll
        for (int j = 0; j < 40; ++j) ostage[j * 257 + t] = z[j] - lse;
    }
    __syncthreads();
    int nodes = n - blockIdx.x * 256;
    if (nodes > 256) nodes = 256;
    int total = nodes * 40;
    size_t base = (size_t)blockIdx.x * 256 * 40;
    for (int i = t; i < total; i += 256) {
        int nl = i / 40;
        int j = i - nl * 40;
        out[base + i] = ostage[j * 257 + nl];
    }
}

extern "C" void kernel_launch(void* const* d_in, const int* in_sizes, int n_in,
                              void* d_out, int out_size, void* d_ws, size_t ws_size,
                              hipStream_t stream) {
    const float* x     = (const float*)d_in[0];
    const int*   src   = (const int*)d_in[1];
    const int*   dst   = (const int*)d_in[2];
    const float* W1    = (const float*)d_in[3];
    const float* b1    = (const float*)d_in[4];
    const float* gamma = (const float*)d_in[5];
    const float* beta  = (const float*)d_in[6];
    const float* Wl    = (const float*)d_in[7];
    const float* bl    = (const float*)d_in[8];
    const float* W2    = (const float*)d_in[9];
    const float* b2    = (const float*)d_in[10];
    float* out = (float*)d_out;

    int n = in_sizes[0] / F_IN;   // 100000
    int e = in_sizes[1];          // 3200000
    int nbkt = (n + RB - 1) >> RB_BITS;   // 196
    int nAlign = (n + 15) & ~15;

    char* wsb = (char*)d_ws;
    int*    temp    = (int*)wsb;      wsb += (size_t)e * 4;
    int*    csr     = (int*)wsb;      wsb += (size_t)e * 4;
    int*    nodeoff = (int*)wsb;      wsb += (size_t)(nAlign + 16) * 4;
    float*  dinv    = (float*)wsb;    wsb += (size_t)nAlign * 4;
    int*    gbcnt   = (int*)wsb;      wsb += NBKT_MAX * 4;
    int*    gboff   = (int*)wsb;      wsb += (NBKT_MAX + 16) * 4;
    int*    gcur    = (int*)wsb;      wsb += NBKT_MAX * 4;
    float*  stats   = (float*)wsb;    wsb += 64 * 4;
    __half* h1h     = (__half*)wsb;   wsb += (size_t)nAlign * H * 2;
    __half* hh      = (__half*)wsb;   wsb += (size_t)nAlign * H * 2;
    float*  hbuf    = (float*)wsb;    wsb += (size_t)nAlign * H * 4;
    float*  agg2    = (float*)wsb;    wsb += (size_t)nAlign * H * 4;

    int nbE = (e + 4095) / 4096;   // 782

    k_zero<<<1, 256, 0, stream>>>(gbcnt, stats);
    k_bcnt<<<nbE, 256, 0, stream>>>(dst, gbcnt, e);
    k_bscan<<<1, 256, 0, stream>>>(gbcnt, gboff, gcur, nodeoff, nbkt, n);
    k_bin<<<(e + BIN_CHUNK - 1) / BIN_CHUNK, 256, 0, stream>>>(src, dst, gcur, temp, e);
    k_sort<<<nbkt, 256, 0, stream>>>(gboff, temp, csr, nodeoff, dinv, n);
    k_mm1<<<(n + 15) / 16, 256, 0, stream>>>(x, W1, dinv, h1h, n);
    k_gather1<<<(n * 8 + 255) / 256, 256, 0, stream>>>(nodeoff, csr, h1h, dinv, b1, hbuf, stats, n);
    k_bncoef<<<1, 16, 0, stream>>>(stats, gamma, beta, (float)n);
    k_hops<<<(n + 255) / 256, 256, 0, stream>>>(hbuf, hh, stats, Wl, bl, dinv, n);
    k_gather2<<<(n * 8 + 255) / 256, 256, 0, stream>>>(nodeoff, csr, hh, dinv, agg2, n);
    k_final<<<(n + 255) / 256, 256, 0, stream>>>(agg2, W2, b2, out, n);
}